// Round 11
// baseline (132.237 us; speedup 1.0000x reference)
//
#include <hip/hip_runtime.h>
#include <math.h>

#define SEQL 2048
#define BATCH 1024
#define CHUNK 64
#define NCH 32

typedef _Float16 f16x8 __attribute__((ext_vector_type(8)));
typedef _Float16 f16x4 __attribute__((ext_vector_type(4)));
typedef _Float16 h2 __attribute__((ext_vector_type(2)));
typedef float f32x4 __attribute__((ext_vector_type(4)));

// ---------------------------------------------------------------------------
// fp16 pack/unpack helpers
// ---------------------------------------------------------------------------
__device__ inline unsigned short f2h(float f) {
    _Float16 h = (_Float16)f;
    return *reinterpret_cast<unsigned short*>(&h);
}
__device__ inline float packh2(float a, float b) {
    return __uint_as_float((unsigned)f2h(a) | ((unsigned)f2h(b) << 16));
}
__device__ inline float hext(float packed, int sh) {
    const unsigned short s = (unsigned short)(__float_as_uint(packed) >> sh);
    _Float16 h = *reinterpret_cast<const _Float16*>(&s);
    return (float)h;
}

__device__ inline void gl2lds16(const void* g, void* l) {
    __builtin_amdgcn_global_load_lds(
        (const __attribute__((address_space(1))) unsigned int*)g,
        (__attribute__((address_space(3))) unsigned int*)l, 16, 0, 0);
}

// DPP cross-lane add: v += dpp_perm(v).
template<int CTRL>
__device__ inline float dppadd(float v) {
    const int p = __builtin_amdgcn_update_dpp(0, __float_as_int(v), CTRL, 0xF, 0xF, true);
    return v + __int_as_float(p);
}

// ---------------------------------------------------------------------------
// Merged fp32->fp16 convert: x (1024 rows, 1775->1792), W1 (2048 rows, same),
// W2 (512 rows, K=2048), W3 (256 rows, K=512).
// ---------------------------------------------------------------------------
__global__ __launch_bounds__(256) void cvt_all(
    const float* __restrict__ x, const float* __restrict__ W1,
    const float* __restrict__ W2, const float* __restrict__ W3,
    _Float16* __restrict__ xh, _Float16* __restrict__ w1h,
    _Float16* __restrict__ w2h, _Float16* __restrict__ w3h)
{
    const int bid = blockIdx.x;
    if (bid < 3072) {
        const float* src; _Float16* dst;
        if (bid < 1024) { src = x + (size_t)bid * 1775;           dst = xh  + (size_t)bid * 1792; }
        else            { src = W1 + (size_t)(bid - 1024) * 1775; dst = w1h + (size_t)(bid - 1024) * 1792; }
        f16x4* dst4 = reinterpret_cast<f16x4*>(dst);
        for (int i = threadIdx.x; i < 448; i += 256) {
            const int k = i * 4;
            float4 v = {0.f, 0.f, 0.f, 0.f};
            if (k + 3 < 1775) v = *reinterpret_cast<const float4*>(&src[k]);
            else {
                if (k     < 1775) v.x = src[k];
                if (k + 1 < 1775) v.y = src[k + 1];
                if (k + 2 < 1775) v.z = src[k + 2];
            }
            f16x4 o; o[0] = (_Float16)v.x; o[1] = (_Float16)v.y; o[2] = (_Float16)v.z; o[3] = (_Float16)v.w;
            dst4[i] = o;
        }
    } else {
        const float* src; _Float16* dst; int nvec;
        if (bid < 3584) { const int r = bid - 3072; src = W2 + (size_t)r * 2048; dst = w2h + (size_t)r * 2048; nvec = 512; }
        else            { const int r = bid - 3584; src = W3 + (size_t)r * 512;  dst = w3h + (size_t)r * 512;  nvec = 128; }
        f16x4* dst4 = reinterpret_cast<f16x4*>(dst);
        for (int i = threadIdx.x; i < nvec; i += 256) {
            const float4 v = reinterpret_cast<const float4*>(src)[i];
            f16x4 o; o[0] = (_Float16)v.x; o[1] = (_Float16)v.y; o[2] = (_Float16)v.z; o[3] = (_Float16)v.w;
            dst4[i] = o;
        }
    }
}

// h3 = relu(bn2(P0)) -> fp16.  2 rows per block, K=512.
__global__ __launch_bounds__(256) void cvt_bnrelu(
    const float* __restrict__ P0,
    const float* __restrict__ sc, const float* __restrict__ tc,
    _Float16* __restrict__ h3)
{
    const int row = blockIdx.x * 2 + (threadIdx.x >> 7);
    const int i = threadIdx.x & 127;
    const float4 p0 = reinterpret_cast<const float4*>(P0 + (size_t)row * 512)[i];
    const float4 sv = reinterpret_cast<const float4*>(sc)[i];
    const float4 tv = reinterpret_cast<const float4*>(tc)[i];
    f16x4 o;
    o[0] = (_Float16)fmaxf(fmaf(sv.x, p0.x, tv.x), 0.f);
    o[1] = (_Float16)fmaxf(fmaf(sv.y, p0.y, tv.y), 0.f);
    o[2] = (_Float16)fmaxf(fmaf(sv.z, p0.z, tv.z), 0.f);
    o[3] = (_Float16)fmaxf(fmaf(sv.w, p0.w, tv.w), 0.f);
    reinterpret_cast<f16x4*>(h3 + (size_t)row * 512)[i] = o;
}

// ---------------------------------------------------------------------------
// fp16 MFMA GEMM (NT), double-buffered LDS (2-phase pipeline, T3 recipe):
// STAGE(tile t+1) is issued BEFORE ds_read+MFMA of tile t, one barrier per
// tile -> HBM latency hides under compute. 64x64 tile, BK=64, 4 waves,
// 16x16x32_f16 MFMA, gl2lds staging, XOR slot swizzle on both sides.
// If bnp != nullptr: epilogue writes per-(m-block, wave-half) column
// sum/sumsq partials (deterministic, no atomics) for a following bn_fin.
// ---------------------------------------------------------------------------
__global__ __launch_bounds__(256) void gemm_f16(
    const _Float16* __restrict__ A, const _Float16* __restrict__ B,
    float* __restrict__ C, int ldc, int Kp, int ksteps,
    float* __restrict__ bnp, int bn_ld)
{
    __shared__ __attribute__((aligned(16))) _Float16 sA[2][64 * 64];  // 16 KB
    __shared__ __attribute__((aligned(16))) _Float16 sB[2][64 * 64];  // 16 KB

    const int tid = threadIdx.x;
    const int wave = tid >> 6;
    const int lane = tid & 63;
    const int m0 = blockIdx.y * 64;
    const int n0 = blockIdx.x * 64;

    const int srow = tid >> 3;          // 0..31
    const int pslot = tid & 7;
    const int gslot = pslot ^ (srow & 7);
    const size_t gk0 = (size_t)gslot * 8;
    const _Float16* gA0 = A + (size_t)(m0 + srow) * Kp + gk0;
    const _Float16* gA1 = A + (size_t)(m0 + 32 + srow) * Kp + gk0;
    const _Float16* gB0 = B + (size_t)(n0 + srow) * Kp + gk0;
    const _Float16* gB1 = B + (size_t)(n0 + 32 + srow) * Kp + gk0;
    const int wdst = wave * 512;

    const int wr = wave >> 1, wc = wave & 1;
    const int li = lane & 15, gq = lane >> 4;
    const int p0s = (gq    ) ^ (li & 7);
    const int p1s = (gq + 4) ^ (li & 7);

    f32x4 acc[2][2];
    #pragma unroll
    for (int i = 0; i < 2; ++i)
        #pragma unroll
        for (int j = 0; j < 2; ++j)
            #pragma unroll
            for (int v = 0; v < 4; ++v) acc[i][j][v] = 0.f;

    // prologue: stage tile 0 into buffer 0
    {
        gl2lds16(gA0, &sA[0][wdst]);
        gl2lds16(gA1, &sA[0][2048 + wdst]);
        gl2lds16(gB0, &sB[0][wdst]);
        gl2lds16(gB1, &sB[0][2048 + wdst]);
    }
    __syncthreads();

    int cur = 0;
    for (int kt = 0; kt < ksteps; ++kt) {
        // issue next-tile stage into the other buffer (hidden under compute)
        if (kt + 1 < ksteps) {
            const size_t go = (size_t)(kt + 1) * 64;
            const int nb = cur ^ 1;
            gl2lds16(gA0 + go, &sA[nb][wdst]);
            gl2lds16(gA1 + go, &sA[nb][2048 + wdst]);
            gl2lds16(gB0 + go, &sB[nb][wdst]);
            gl2lds16(gB1 + go, &sB[nb][2048 + wdst]);
        }

        f16x8 af[2][2], bg[2][2];
        #pragma unroll
        for (int mi = 0; mi < 2; ++mi) {
            const int rb = (wr * 32 + mi * 16 + li) * 64;
            af[mi][0] = *(const f16x8*)&sA[cur][rb + p0s * 8];
            af[mi][1] = *(const f16x8*)&sA[cur][rb + p1s * 8];
        }
        #pragma unroll
        for (int ni = 0; ni < 2; ++ni) {
            const int rb = (wc * 32 + ni * 16 + li) * 64;
            bg[ni][0] = *(const f16x8*)&sB[cur][rb + p0s * 8];
            bg[ni][1] = *(const f16x8*)&sB[cur][rb + p1s * 8];
        }
        #pragma unroll
        for (int mi = 0; mi < 2; ++mi)
            #pragma unroll
            for (int ni = 0; ni < 2; ++ni) {
                acc[mi][ni] = __builtin_amdgcn_mfma_f32_16x16x32_f16(af[mi][0], bg[ni][0], acc[mi][ni], 0, 0, 0);
                acc[mi][ni] = __builtin_amdgcn_mfma_f32_16x16x32_f16(af[mi][1], bg[ni][1], acc[mi][ni], 0, 0, 0);
            }
        __syncthreads();   // drains next-tile stage; reads of cur are done
        cur ^= 1;
    }

    #pragma unroll
    for (int mi = 0; mi < 2; ++mi)
        #pragma unroll
        for (int ni = 0; ni < 2; ++ni) {
            const int col = n0 + wc * 32 + ni * 16 + li;
            #pragma unroll
            for (int i = 0; i < 4; ++i) {
                const int row = m0 + wr * 32 + mi * 16 + gq * 4 + i;
                C[(size_t)row * ldc + col] = acc[mi][ni][i];
            }
        }

    // ---- optional fused batchnorm partials -------------------------------
    if (bnp) {
        #pragma unroll
        for (int ni = 0; ni < 2; ++ni) {
            float ps = 0.f, pq = 0.f;
            #pragma unroll
            for (int mi = 0; mi < 2; ++mi)
                #pragma unroll
                for (int i = 0; i < 4; ++i) {
                    const float v = acc[mi][ni][i];
                    ps += v; pq += v * v;
                }
            ps += __shfl_xor(ps, 16); ps += __shfl_xor(ps, 32);
            pq += __shfl_xor(pq, 16); pq += __shfl_xor(pq, 32);
            if (gq == 0) {
                const int col = n0 + wc * 32 + ni * 16 + li;
                const int grp = blockIdx.y * 2 + wr;
                bnp[(size_t)(grp * 2    ) * bn_ld + col] = ps;
                bnp[(size_t)(grp * 2 + 1) * bn_ld + col] = pq;
            }
        }
    }
}

// ---------------------------------------------------------------------------
__global__ __launch_bounds__(256) void bn_fin(
    const float* __restrict__ part, int RG, int ld, float inv_rows,
    const float* __restrict__ g, const float* __restrict__ b,
    float* __restrict__ s, float* __restrict__ t)
{
    const int col = blockIdx.x * 256 + threadIdx.x;
    if (col >= ld) return;
    float sum = 0.f, sq = 0.f;
    for (int z = 0; z < RG; ++z) {
        sum += part[((size_t)z * 2    ) * ld + col];
        sq  += part[((size_t)z * 2 + 1) * ld + col];
    }
    const float mean = sum * inv_rows;
    const float var = fmaxf(sq * inv_rows - mean * mean, 0.f);
    const float rstd = 1.0f / sqrtf(var + 1e-5f);
    const float sv = g[col] * rstd;
    s[col] = sv;
    t[col] = b[col] - mean * sv;
}

// ---------------------------------------------------------------------------
// Chunked-parallel mamba scan, v9 (unchanged from round 10): step-major pk,
// e-paired lanes, 32 chunks x 64 steps, DPP reduction, fp16 output.
// ---------------------------------------------------------------------------
__global__ __launch_bounds__(512, 8) void mamba_scan9(
    const float* __restrict__ Y, _Float16* __restrict__ a2,
    const float* __restrict__ s1, const float* __restrict__ t1,
    const float* __restrict__ Win, const float* __restrict__ convw,
    const float* __restrict__ convb, const float* __restrict__ Wx,
    const float* __restrict__ Wdt, const float* __restrict__ bdt,
    const float* __restrict__ Alog, const float* __restrict__ Dp,
    const float* __restrict__ Wout)
{
    __shared__ __align__(16) float4 pk[SEQL];   // 32 KB, index = (i<<5) + ch
    __shared__ float Pa[2][NCH][16];            // 4 KB
    __shared__ float Sa[2][NCH][16];            // 4 KB (becomes Hin in-place)

    const int tid = threadIdx.x;
    const int row = blockIdx.x;
    const float* yrow = Y + (size_t)row * SEQL;
    _Float16* a2row = a2 + (size_t)row * SEQL;

    // ---- phase A': steps [4*tid, 4*tid+4) ---------------------------------
    {
        const int l0 = tid * 4;
        float4 ym = {0.f,0.f,0.f,0.f}, sm = {0.f,0.f,0.f,0.f}, tm = {0.f,0.f,0.f,0.f};
        if (tid > 0) {
            ym = *reinterpret_cast<const float4*>(&yrow[l0 - 4]);
            sm = *reinterpret_cast<const float4*>(&s1[l0 - 4]);
            tm = *reinterpret_cast<const float4*>(&t1[l0 - 4]);
        }
        const float4 y0 = *reinterpret_cast<const float4*>(&yrow[l0]);
        const float4 s0 = *reinterpret_cast<const float4*>(&s1[l0]);
        const float4 t0 = *reinterpret_cast<const float4*>(&t1[l0]);

        float ua[8];
        ua[0] = fmaf(sm.x, ym.x, tm.x);
        ua[1] = fmaf(sm.y, ym.y, tm.y);
        ua[2] = fmaf(sm.z, ym.z, tm.z);
        ua[3] = fmaf(sm.w, ym.w, tm.w);
        ua[4] = fmaf(s0.x, y0.x, t0.x);
        ua[5] = fmaf(s0.y, y0.y, t0.y);
        ua[6] = fmaf(s0.z, y0.z, t0.z);
        ua[7] = fmaf(s0.w, y0.w, t0.w);

        const float wi0 = Win[0], wi1 = Win[1];
        const float wz0 = Win[2], wz1 = Win[3];
        const float wo0 = Wout[0], wo1 = Wout[1];
        const float cw00 = convw[0], cw01 = convw[1], cw02 = convw[2], cw03 = convw[3];
        const float cw10 = convw[4], cw11 = convw[5], cw12 = convw[6], cw13 = convw[7];
        const float cb0 = convb[0], cb1 = convb[1];
        const float wx00 = Wx[0], wx01 = Wx[1];
        const float wdt0 = Wdt[0], wdt1 = Wdt[1];
        const float bdt0 = bdt[0], bdt1 = bdt[1];

        #pragma unroll
        for (int j = 0; j < 4; ++j) {
            const int l = l0 + j;
            const float u0 = ua[j + 4], um1 = ua[j + 3], um2 = ua[j + 2], um3 = ua[j + 1];
            const float c0 = fmaf(wi0, cw00 * um3 + cw01 * um2 + cw02 * um1 + cw03 * u0, cb0);
            const float c1 = fmaf(wi1, cw10 * um3 + cw11 * um2 + cw12 * um1 + cw13 * u0, cb1);
            const float xs0 = c0 / (1.f + __expf(-c0));
            const float xs1 = c1 / (1.f + __expf(-c1));
            const float d0 = xs0 * wx00 + xs1 * wx01;
            const float dt0 = __logf(1.f + __expf(fmaf(d0, wdt0, bdt0)));
            const float dt1 = __logf(1.f + __expf(fmaf(d0, wdt1, bdt1)));
            const float z0 = u0 * wz0, z1 = u0 * wz1;
            const float g0 = (z0 / (1.f + __expf(-z0))) * wo0;
            const float g1 = (z1 / (1.f + __expf(-z1))) * wo1;
            float4 rec;
            rec.x = dt0; rec.y = dt1;
            rec.z = packh2(xs0, xs1);
            rec.w = packh2(g0, g1);
            pk[((l & 63) << 5) + (l >> 6)] = rec;   // step-major
        }
    }
    __syncthreads();

    // ---- lane decomposition: chunk = 16 lanes, lane = n -------------------
    const int ch = tid >> 4;       // chunk 0..31
    const int n  = tid & 15;

    const float A0 = -__expf(Alog[n])      * 1.44269504f;  // e=0, * log2(e)
    const float A1 = -__expf(Alog[16 + n]) * 1.44269504f;  // e=1
    h2 wxB2, wxC2;
    wxB2[0] = (_Float16)Wx[(1 + n) * 2 + 0];
    wxB2[1] = (_Float16)Wx[(1 + n) * 2 + 1];
    wxC2[0] = (_Float16)Wx[(17 + n) * 2 + 0];
    wxC2[1] = (_Float16)Wx[(17 + n) * 2 + 1];

    // ---- phase A'': dual local scan, h_in = 0 -----------------------------
    {
        float h0 = 0.f, h1 = 0.f, p0 = 1.f, p1 = 1.f;
        for (int i0 = 0; i0 < CHUNK; i0 += 8) {
            #pragma unroll
            for (int j = 0; j < 8; ++j) {
                const float4 v = pk[((i0 + j) << 5) + ch];
                const h2 xs2 = __builtin_bit_cast(h2, v.z);
                const float Bn = __builtin_amdgcn_fdot2(xs2, wxB2, 0.f, false);
                const float xs0 = hext(v.z, 0), xs1 = hext(v.z, 16);
                const float dA0 = __builtin_amdgcn_exp2f(v.x * A0);
                const float dA1 = __builtin_amdgcn_exp2f(v.y * A1);
                h0 = fmaf(h0, dA0, (v.x * xs0) * Bn);
                h1 = fmaf(h1, dA1, (v.y * xs1) * Bn);
                p0 *= dA0; p1 *= dA1;
            }
        }
        Pa[0][ch][n] = p0; Pa[1][ch][n] = p1;
        Sa[0][ch][n] = h0; Sa[1][ch][n] = h1;
    }
    __syncthreads();

    // ---- phase B: serial chunk combine (in-place Hin into Sa) -------------
    if (tid < 32) {
        const int e = tid >> 4, nn = tid & 15;
        float H = 0.f;
        #pragma unroll
        for (int cc = 0; cc < NCH; ++cc) {
            const float Pv = Pa[e][cc][nn];
            const float Sv = Sa[e][cc][nn];
            Sa[e][cc][nn] = H;             // H_in for chunk cc
            H = fmaf(Pv, H, Sv);
        }
    }
    __syncthreads();

    // ---- phase C: seeded dual re-scan + fp16 output -----------------------
    {
        h2 D2h;
        D2h[0] = (_Float16)Dp[0];
        D2h[1] = (_Float16)Dp[1];
        const int base = ch * CHUNK;
        float h0 = Sa[0][ch][n], h1 = Sa[1][ch][n];
        for (int i0 = 0; i0 < CHUNK; i0 += 8) {
            float qs[8];
            #pragma unroll
            for (int j = 0; j < 8; ++j) {
                const float4 v = pk[((i0 + j) << 5) + ch];
                const h2 xs2 = __builtin_bit_cast(h2, v.z);
                const h2 gg2 = __builtin_bit_cast(h2, v.w);
                const float Bn = __builtin_amdgcn_fdot2(xs2, wxB2, 0.f, false);
                const float Cn = __builtin_amdgcn_fdot2(xs2, wxC2, 0.f, false);
                const float xs0 = hext(v.z, 0), xs1 = hext(v.z, 16);
                const float g0 = hext(v.w, 0),  g1 = hext(v.w, 16);
                const float dA0 = __builtin_amdgcn_exp2f(v.x * A0);
                const float dA1 = __builtin_amdgcn_exp2f(v.y * A1);
                h0 = fmaf(h0, dA0, (v.x * xs0) * Bn);
                h1 = fmaf(h1, dA1, (v.y * xs1) * Bn);
                float t = h0 * g0;
                t = fmaf(h1, g1, t);
                float q = t * Cn;
                q = dppadd<0xB1>(q);    // xor1
                q = dppadd<0x4E>(q);    // xor2
                q = dppadd<0x141>(q);   // xor4 (row_half_mirror)
                q = dppadd<0x140>(q);   // xor8 (row_mirror) -> 16-lane sum
                const h2 dgh = D2h * gg2;                       // v_pk_mul_f16
                const float dterm = __builtin_amdgcn_fdot2(xs2, dgh, 0.f, false);
                qs[j] = q + dterm;
            }
            if (n == 0) {
                float4 st;
                st.x = __builtin_bit_cast(float, __builtin_amdgcn_cvt_pkrtz(qs[0], qs[1]));
                st.y = __builtin_bit_cast(float, __builtin_amdgcn_cvt_pkrtz(qs[2], qs[3]));
                st.z = __builtin_bit_cast(float, __builtin_amdgcn_cvt_pkrtz(qs[4], qs[5]));
                st.w = __builtin_bit_cast(float, __builtin_amdgcn_cvt_pkrtz(qs[6], qs[7]));
                *reinterpret_cast<float4*>(&a2row[base + i0]) = st;
            }
        }
    }
}

// ---------------------------------------------------------------------------
extern "C" void kernel_launch(void* const* d_in, const int* in_sizes, int n_in,
                              void* d_out, int out_size, void* d_ws, size_t ws_size,
                              hipStream_t stream)
{
    const float* x     = (const float*)d_in[0];
    const float* W1    = (const float*)d_in[1];
    const float* g1    = (const float*)d_in[2];
    const float* b1    = (const float*)d_in[3];
    const float* Win   = (const float*)d_in[4];
    const float* convw = (const float*)d_in[5];
    const float* convb = (const float*)d_in[6];
    const float* Wx    = (const float*)d_in[7];
    const float* Wdt   = (const float*)d_in[8];
    const float* bdt   = (const float*)d_in[9];
    const float* Alog  = (const float*)d_in[10];
    const float* Dp    = (const float*)d_in[11];
    const float* Wout  = (const float*)d_in[12];
    const float* W2    = (const float*)d_in[13];
    const float* g2    = (const float*)d_in[14];
    const float* b2    = (const float*)d_in[15];
    const float* W3    = (const float*)d_in[16];

    unsigned char* base = (unsigned char*)d_ws;   // all regions disjoint
    float* C1 = (float*)(base + 0);               //  8,388,608
    float* P0 = (float*)(base + 8388608);         //  2,097,152
    float* s1 = (float*)(base + 12582912);        //  8 KB
    float* t1 = (float*)(base + 12591104);        //  8 KB
    float* s2 = (float*)(base + 12599296);        //  2 KB
    float* t2 = (float*)(base + 12601344);        //  2 KB
    float* bnp = (float*)(base + 12615680);       //  524,288 (32 grp x 2 x 2048)
    _Float16* a2  = (_Float16*)(base + 13172736); //  4,194,304
    _Float16* xh  = (_Float16*)(base + 17367040); //  3,670,016
    _Float16* w1h = (_Float16*)(base + 21037056); //  7,340,032
    _Float16* w2h = (_Float16*)(base + 28377088); //  2,097,152
    _Float16* w3h = (_Float16*)(base + 30474240); //    262,144
    _Float16* h3h = (_Float16*)(base + 30736384); //  1,048,576  (end ~31.8 MB)

    // 1) all fp32->fp16 conversions in one grid-filling dispatch
    cvt_all<<<3840, 256, 0, stream>>>(x, W1, W2, W3, xh, w1h, w2h, w3h);

    // 2) GEMM1: C1 = x @ W1^T ; fused BN1 partials into epilogue (dbuf)
    gemm_f16<<<dim3(32, 16), 256, 0, stream>>>(
        xh, w1h, C1, 2048, 1792, 28, bnp, 2048);

    // 3) BN1 finalize (32 partial groups)
    bn_fin<<<8, 256, 0, stream>>>(bnp, 32, 2048, 1.0f / 1024.f, g1, b1, s1, t1);

    // 4) mamba scan: reads C1, writes a2 (fp16)
    mamba_scan9<<<1024, 512, 0, stream>>>(C1, a2, s1, t1, Win, convw, convb,
                                          Wx, Wdt, bdt, Alog, Dp, Wout);

    // 5) GEMM2 (full-K, dbuf): P0 = a2 @ W2^T ; fused BN2 partials
    gemm_f16<<<dim3(8, 16), 256, 0, stream>>>(
        a2, w2h, P0, 512, 2048, 32, bnp, 512);

    // 6) BN2 finalize (32 partial groups over 512 cols)
    bn_fin<<<2, 256, 0, stream>>>(bnp, 32, 512, 1.0f / 1024.f, g2, b2, s2, t2);

    // 7) h3 = relu(bn2(P0)) -> fp16
    cvt_bnrelu<<<512, 256, 0, stream>>>(P0, s2, t2, h3h);

    // 8) GEMM3: d_out = h3 @ W3^T  (1024x256, K=512, dbuf)
    gemm_f16<<<dim3(4, 16), 256, 0, stream>>>(
        h3h, w3h, (float*)d_out, 256, 512, 8, nullptr, 0);
}

// Round 12
// 126.751 us; speedup vs baseline: 1.0433x; 1.0433x over previous
//
#include <hip/hip_runtime.h>
#include <math.h>

#define SEQL 2048
#define BATCH 1024
#define CHUNK 64
#define NCH 32

typedef _Float16 f16x8 __attribute__((ext_vector_type(8)));
typedef _Float16 f16x4 __attribute__((ext_vector_type(4)));
typedef _Float16 h2 __attribute__((ext_vector_type(2)));
typedef float f32x4 __attribute__((ext_vector_type(4)));

// ---------------------------------------------------------------------------
// fp16 pack/unpack helpers
// ---------------------------------------------------------------------------
__device__ inline unsigned short f2h(float f) {
    _Float16 h = (_Float16)f;
    return *reinterpret_cast<unsigned short*>(&h);
}
__device__ inline float packh2(float a, float b) {
    return __uint_as_float((unsigned)f2h(a) | ((unsigned)f2h(b) << 16));
}
__device__ inline float hext(float packed, int sh) {
    const unsigned short s = (unsigned short)(__float_as_uint(packed) >> sh);
    _Float16 h = *reinterpret_cast<const _Float16*>(&s);
    return (float)h;
}

__device__ inline void gl2lds16(const void* g, void* l) {
    __builtin_amdgcn_global_load_lds(
        (const __attribute__((address_space(1))) unsigned int*)g,
        (__attribute__((address_space(3))) unsigned int*)l, 16, 0, 0);
}

// DPP cross-lane add: v += dpp_perm(v).
template<int CTRL>
__device__ inline float dppadd(float v) {
    const int p = __builtin_amdgcn_update_dpp(0, __float_as_int(v), CTRL, 0xF, 0xF, true);
    return v + __int_as_float(p);
}

// ---------------------------------------------------------------------------
// Merged fp32->fp16 convert: x (1024 rows, 1775->1792), W1 (2048 rows, same),
// W2 (512 rows, K=2048), W3 (256 rows, K=512).
// ---------------------------------------------------------------------------
__global__ __launch_bounds__(256) void cvt_all(
    const float* __restrict__ x, const float* __restrict__ W1,
    const float* __restrict__ W2, const float* __restrict__ W3,
    _Float16* __restrict__ xh, _Float16* __restrict__ w1h,
    _Float16* __restrict__ w2h, _Float16* __restrict__ w3h)
{
    const int bid = blockIdx.x;
    if (bid < 3072) {
        const float* src; _Float16* dst;
        if (bid < 1024) { src = x + (size_t)bid * 1775;           dst = xh  + (size_t)bid * 1792; }
        else            { src = W1 + (size_t)(bid - 1024) * 1775; dst = w1h + (size_t)(bid - 1024) * 1792; }
        f16x4* dst4 = reinterpret_cast<f16x4*>(dst);
        for (int i = threadIdx.x; i < 448; i += 256) {
            const int k = i * 4;
            float4 v = {0.f, 0.f, 0.f, 0.f};
            if (k + 3 < 1775) v = *reinterpret_cast<const float4*>(&src[k]);
            else {
                if (k     < 1775) v.x = src[k];
                if (k + 1 < 1775) v.y = src[k + 1];
                if (k + 2 < 1775) v.z = src[k + 2];
            }
            f16x4 o; o[0] = (_Float16)v.x; o[1] = (_Float16)v.y; o[2] = (_Float16)v.z; o[3] = (_Float16)v.w;
            dst4[i] = o;
        }
    } else {
        const float* src; _Float16* dst; int nvec;
        if (bid < 3584) { const int r = bid - 3072; src = W2 + (size_t)r * 2048; dst = w2h + (size_t)r * 2048; nvec = 512; }
        else            { const int r = bid - 3584; src = W3 + (size_t)r * 512;  dst = w3h + (size_t)r * 512;  nvec = 128; }
        f16x4* dst4 = reinterpret_cast<f16x4*>(dst);
        for (int i = threadIdx.x; i < nvec; i += 256) {
            const float4 v = reinterpret_cast<const float4*>(src)[i];
            f16x4 o; o[0] = (_Float16)v.x; o[1] = (_Float16)v.y; o[2] = (_Float16)v.z; o[3] = (_Float16)v.w;
            dst4[i] = o;
        }
    }
}

// h3 = relu(bn2(P0+P1)) -> fp16.  2 rows per block, K=512.
__global__ __launch_bounds__(256) void cvt_bnrelu(
    const float* __restrict__ P0, const float* __restrict__ P1,
    const float* __restrict__ sc, const float* __restrict__ tc,
    _Float16* __restrict__ h3)
{
    const int row = blockIdx.x * 2 + (threadIdx.x >> 7);
    const int i = threadIdx.x & 127;
    const float4 p0 = reinterpret_cast<const float4*>(P0 + (size_t)row * 512)[i];
    const float4 p1 = reinterpret_cast<const float4*>(P1 + (size_t)row * 512)[i];
    const float4 sv = reinterpret_cast<const float4*>(sc)[i];
    const float4 tv = reinterpret_cast<const float4*>(tc)[i];
    f16x4 o;
    o[0] = (_Float16)fmaxf(fmaf(sv.x, p0.x + p1.x, tv.x), 0.f);
    o[1] = (_Float16)fmaxf(fmaf(sv.y, p0.y + p1.y, tv.y), 0.f);
    o[2] = (_Float16)fmaxf(fmaf(sv.z, p0.z + p1.z, tv.z), 0.f);
    o[3] = (_Float16)fmaxf(fmaf(sv.w, p0.w + p1.w, tv.w), 0.f);
    reinterpret_cast<f16x4*>(h3 + (size_t)row * 512)[i] = o;
}

// ---------------------------------------------------------------------------
// fp16 MFMA GEMM (NT), double-buffered LDS: STAGE(t+1) issued before
// ds_read+MFMA of tile t, one barrier per tile. 64x64 tile, BK=64, 4 waves,
// 16x16x32_f16 MFMA, gl2lds staging, XOR slot swizzle on both sides.
// Split-K over blockIdx.z (C += z*coff). If bnp != nullptr (non-split only):
// epilogue writes per-(m-block, wave-half) column sum/sumsq partials.
// ---------------------------------------------------------------------------
__global__ __launch_bounds__(256) void gemm_f16(
    const _Float16* __restrict__ A, const _Float16* __restrict__ B,
    float* __restrict__ C, int ldc, int Kp, int ksteps, size_t coff,
    float* __restrict__ bnp, int bn_ld)
{
    __shared__ __attribute__((aligned(16))) _Float16 sA[2][64 * 64];  // 16 KB
    __shared__ __attribute__((aligned(16))) _Float16 sB[2][64 * 64];  // 16 KB

    const int tid = threadIdx.x;
    const int wave = tid >> 6;
    const int lane = tid & 63;
    const int m0 = blockIdx.y * 64;
    const int n0 = blockIdx.x * 64;
    C += (size_t)blockIdx.z * coff;

    const int srow = tid >> 3;          // 0..31
    const int pslot = tid & 7;
    const int gslot = pslot ^ (srow & 7);
    const size_t gk0 = (size_t)blockIdx.z * ksteps * 64 + (size_t)gslot * 8;
    const _Float16* gA0 = A + (size_t)(m0 + srow) * Kp + gk0;
    const _Float16* gA1 = A + (size_t)(m0 + 32 + srow) * Kp + gk0;
    const _Float16* gB0 = B + (size_t)(n0 + srow) * Kp + gk0;
    const _Float16* gB1 = B + (size_t)(n0 + 32 + srow) * Kp + gk0;
    const int wdst = wave * 512;

    const int wr = wave >> 1, wc = wave & 1;
    const int li = lane & 15, gq = lane >> 4;
    const int p0s = (gq    ) ^ (li & 7);
    const int p1s = (gq + 4) ^ (li & 7);

    f32x4 acc[2][2];
    #pragma unroll
    for (int i = 0; i < 2; ++i)
        #pragma unroll
        for (int j = 0; j < 2; ++j)
            #pragma unroll
            for (int v = 0; v < 4; ++v) acc[i][j][v] = 0.f;

    // prologue: stage tile 0 into buffer 0
    gl2lds16(gA0, &sA[0][wdst]);
    gl2lds16(gA1, &sA[0][2048 + wdst]);
    gl2lds16(gB0, &sB[0][wdst]);
    gl2lds16(gB1, &sB[0][2048 + wdst]);
    __syncthreads();

    int cur = 0;
    for (int kt = 0; kt < ksteps; ++kt) {
        if (kt + 1 < ksteps) {
            const size_t go = (size_t)(kt + 1) * 64;
            const int nb = cur ^ 1;
            gl2lds16(gA0 + go, &sA[nb][wdst]);
            gl2lds16(gA1 + go, &sA[nb][2048 + wdst]);
            gl2lds16(gB0 + go, &sB[nb][wdst]);
            gl2lds16(gB1 + go, &sB[nb][2048 + wdst]);
        }

        f16x8 af[2][2], bg[2][2];
        #pragma unroll
        for (int mi = 0; mi < 2; ++mi) {
            const int rb = (wr * 32 + mi * 16 + li) * 64;
            af[mi][0] = *(const f16x8*)&sA[cur][rb + p0s * 8];
            af[mi][1] = *(const f16x8*)&sA[cur][rb + p1s * 8];
        }
        #pragma unroll
        for (int ni = 0; ni < 2; ++ni) {
            const int rb = (wc * 32 + ni * 16 + li) * 64;
            bg[ni][0] = *(const f16x8*)&sB[cur][rb + p0s * 8];
            bg[ni][1] = *(const f16x8*)&sB[cur][rb + p1s * 8];
        }
        #pragma unroll
        for (int mi = 0; mi < 2; ++mi)
            #pragma unroll
            for (int ni = 0; ni < 2; ++ni) {
                acc[mi][ni] = __builtin_amdgcn_mfma_f32_16x16x32_f16(af[mi][0], bg[ni][0], acc[mi][ni], 0, 0, 0);
                acc[mi][ni] = __builtin_amdgcn_mfma_f32_16x16x32_f16(af[mi][1], bg[ni][1], acc[mi][ni], 0, 0, 0);
            }
        __syncthreads();
        cur ^= 1;
    }

    #pragma unroll
    for (int mi = 0; mi < 2; ++mi)
        #pragma unroll
        for (int ni = 0; ni < 2; ++ni) {
            const int col = n0 + wc * 32 + ni * 16 + li;
            #pragma unroll
            for (int i = 0; i < 4; ++i) {
                const int row = m0 + wr * 32 + mi * 16 + gq * 4 + i;
                C[(size_t)row * ldc + col] = acc[mi][ni][i];
            }
        }

    // ---- optional fused batchnorm partials -------------------------------
    if (bnp) {
        #pragma unroll
        for (int ni = 0; ni < 2; ++ni) {
            float ps = 0.f, pq = 0.f;
            #pragma unroll
            for (int mi = 0; mi < 2; ++mi)
                #pragma unroll
                for (int i = 0; i < 4; ++i) {
                    const float v = acc[mi][ni][i];
                    ps += v; pq += v * v;
                }
            ps += __shfl_xor(ps, 16); ps += __shfl_xor(ps, 32);
            pq += __shfl_xor(pq, 16); pq += __shfl_xor(pq, 32);
            if (gq == 0) {
                const int col = n0 + wc * 32 + ni * 16 + li;
                const int grp = blockIdx.y * 2 + wr;
                bnp[(size_t)(grp * 2    ) * bn_ld + col] = ps;
                bnp[(size_t)(grp * 2 + 1) * bn_ld + col] = pq;
            }
        }
    }
}

// ---------------------------------------------------------------------------
// Two-pass batchnorm stats (pass 1 used for BN2 over P0+P1).
// ---------------------------------------------------------------------------
__global__ __launch_bounds__(256) void bn_part(
    const float* __restrict__ X, const float* __restrict__ X2,
    int rows_per, int ld, float* __restrict__ part)
{
    __shared__ float rs[4][64], rq[4][64];
    const int tid = threadIdx.x;
    const int c = tid & 63, rg4 = tid >> 6;
    const int col = blockIdx.x * 64 + c;
    const int r0 = blockIdx.y * rows_per;
    float sum = 0.f, sq = 0.f;
    for (int r = rg4; r < rows_per; r += 4) {
        const size_t idx = (size_t)(r0 + r) * ld + col;
        float v = X[idx];
        if (X2) v += X2[idx];
        sum += v; sq += v * v;
    }
    rs[rg4][c] = sum; rq[rg4][c] = sq;
    __syncthreads();
    if (rg4 == 0) {
        sum = rs[0][c] + rs[1][c] + rs[2][c] + rs[3][c];
        sq  = rq[0][c] + rq[1][c] + rq[2][c] + rq[3][c];
        part[((size_t)blockIdx.y * 2    ) * ld + col] = sum;
        part[((size_t)blockIdx.y * 2 + 1) * ld + col] = sq;
    }
}

__global__ __launch_bounds__(256) void bn_fin(
    const float* __restrict__ part, int RG, int ld, float inv_rows,
    const float* __restrict__ g, const float* __restrict__ b,
    float* __restrict__ s, float* __restrict__ t)
{
    const int col = blockIdx.x * 256 + threadIdx.x;
    if (col >= ld) return;
    float sum = 0.f, sq = 0.f;
    for (int z = 0; z < RG; ++z) {
        sum += part[((size_t)z * 2    ) * ld + col];
        sq  += part[((size_t)z * 2 + 1) * ld + col];
    }
    const float mean = sum * inv_rows;
    const float var = fmaxf(sq * inv_rows - mean * mean, 0.f);
    const float rstd = 1.0f / sqrtf(var + 1e-5f);
    const float sv = g[col] * rstd;
    s[col] = sv;
    t[col] = b[col] - mean * sv;
}

// ---------------------------------------------------------------------------
// Chunked-parallel mamba scan, v9 (unchanged): step-major pk, e-paired lanes,
// 32 chunks x 64 steps, DPP reduction, fp16 output.
// ---------------------------------------------------------------------------
__global__ __launch_bounds__(512, 8) void mamba_scan9(
    const float* __restrict__ Y, _Float16* __restrict__ a2,
    const float* __restrict__ s1, const float* __restrict__ t1,
    const float* __restrict__ Win, const float* __restrict__ convw,
    const float* __restrict__ convb, const float* __restrict__ Wx,
    const float* __restrict__ Wdt, const float* __restrict__ bdt,
    const float* __restrict__ Alog, const float* __restrict__ Dp,
    const float* __restrict__ Wout)
{
    __shared__ __align__(16) float4 pk[SEQL];   // 32 KB, index = (i<<5) + ch
    __shared__ float Pa[2][NCH][16];            // 4 KB
    __shared__ float Sa[2][NCH][16];            // 4 KB (becomes Hin in-place)

    const int tid = threadIdx.x;
    const int row = blockIdx.x;
    const float* yrow = Y + (size_t)row * SEQL;
    _Float16* a2row = a2 + (size_t)row * SEQL;

    // ---- phase A': steps [4*tid, 4*tid+4) ---------------------------------
    {
        const int l0 = tid * 4;
        float4 ym = {0.f,0.f,0.f,0.f}, sm = {0.f,0.f,0.f,0.f}, tm = {0.f,0.f,0.f,0.f};
        if (tid > 0) {
            ym = *reinterpret_cast<const float4*>(&yrow[l0 - 4]);
            sm = *reinterpret_cast<const float4*>(&s1[l0 - 4]);
            tm = *reinterpret_cast<const float4*>(&t1[l0 - 4]);
        }
        const float4 y0 = *reinterpret_cast<const float4*>(&yrow[l0]);
        const float4 s0 = *reinterpret_cast<const float4*>(&s1[l0]);
        const float4 t0 = *reinterpret_cast<const float4*>(&t1[l0]);

        float ua[8];
        ua[0] = fmaf(sm.x, ym.x, tm.x);
        ua[1] = fmaf(sm.y, ym.y, tm.y);
        ua[2] = fmaf(sm.z, ym.z, tm.z);
        ua[3] = fmaf(sm.w, ym.w, tm.w);
        ua[4] = fmaf(s0.x, y0.x, t0.x);
        ua[5] = fmaf(s0.y, y0.y, t0.y);
        ua[6] = fmaf(s0.z, y0.z, t0.z);
        ua[7] = fmaf(s0.w, y0.w, t0.w);

        const float wi0 = Win[0], wi1 = Win[1];
        const float wz0 = Win[2], wz1 = Win[3];
        const float wo0 = Wout[0], wo1 = Wout[1];
        const float cw00 = convw[0], cw01 = convw[1], cw02 = convw[2], cw03 = convw[3];
        const float cw10 = convw[4], cw11 = convw[5], cw12 = convw[6], cw13 = convw[7];
        const float cb0 = convb[0], cb1 = convb[1];
        const float wx00 = Wx[0], wx01 = Wx[1];
        const float wdt0 = Wdt[0], wdt1 = Wdt[1];
        const float bdt0 = bdt[0], bdt1 = bdt[1];

        #pragma unroll
        for (int j = 0; j < 4; ++j) {
            const int l = l0 + j;
            const float u0 = ua[j + 4], um1 = ua[j + 3], um2 = ua[j + 2], um3 = ua[j + 1];
            const float c0 = fmaf(wi0, cw00 * um3 + cw01 * um2 + cw02 * um1 + cw03 * u0, cb0);
            const float c1 = fmaf(wi1, cw10 * um3 + cw11 * um2 + cw12 * um1 + cw13 * u0, cb1);
            const float xs0 = c0 / (1.f + __expf(-c0));
            const float xs1 = c1 / (1.f + __expf(-c1));
            const float d0 = xs0 * wx00 + xs1 * wx01;
            const float dt0 = __logf(1.f + __expf(fmaf(d0, wdt0, bdt0)));
            const float dt1 = __logf(1.f + __expf(fmaf(d0, wdt1, bdt1)));
            const float z0 = u0 * wz0, z1 = u0 * wz1;
            const float g0 = (z0 / (1.f + __expf(-z0))) * wo0;
            const float g1 = (z1 / (1.f + __expf(-z1))) * wo1;
            float4 rec;
            rec.x = dt0; rec.y = dt1;
            rec.z = packh2(xs0, xs1);
            rec.w = packh2(g0, g1);
            pk[((l & 63) << 5) + (l >> 6)] = rec;   // step-major
        }
    }
    __syncthreads();

    // ---- lane decomposition: chunk = 16 lanes, lane = n -------------------
    const int ch = tid >> 4;       // chunk 0..31
    const int n  = tid & 15;

    const float A0 = -__expf(Alog[n])      * 1.44269504f;  // e=0, * log2(e)
    const float A1 = -__expf(Alog[16 + n]) * 1.44269504f;  // e=1
    h2 wxB2, wxC2;
    wxB2[0] = (_Float16)Wx[(1 + n) * 2 + 0];
    wxB2[1] = (_Float16)Wx[(1 + n) * 2 + 1];
    wxC2[0] = (_Float16)Wx[(17 + n) * 2 + 0];
    wxC2[1] = (_Float16)Wx[(17 + n) * 2 + 1];

    // ---- phase A'': dual local scan, h_in = 0 -----------------------------
    {
        float h0 = 0.f, h1 = 0.f, p0 = 1.f, p1 = 1.f;
        for (int i0 = 0; i0 < CHUNK; i0 += 8) {
            #pragma unroll
            for (int j = 0; j < 8; ++j) {
                const float4 v = pk[((i0 + j) << 5) + ch];
                const h2 xs2 = __builtin_bit_cast(h2, v.z);
                const float Bn = __builtin_amdgcn_fdot2(xs2, wxB2, 0.f, false);
                const float xs0 = hext(v.z, 0), xs1 = hext(v.z, 16);
                const float dA0 = __builtin_amdgcn_exp2f(v.x * A0);
                const float dA1 = __builtin_amdgcn_exp2f(v.y * A1);
                h0 = fmaf(h0, dA0, (v.x * xs0) * Bn);
                h1 = fmaf(h1, dA1, (v.y * xs1) * Bn);
                p0 *= dA0; p1 *= dA1;
            }
        }
        Pa[0][ch][n] = p0; Pa[1][ch][n] = p1;
        Sa[0][ch][n] = h0; Sa[1][ch][n] = h1;
    }
    __syncthreads();

    // ---- phase B: serial chunk combine (in-place Hin into Sa) -------------
    if (tid < 32) {
        const int e = tid >> 4, nn = tid & 15;
        float H = 0.f;
        #pragma unroll
        for (int cc = 0; cc < NCH; ++cc) {
            const float Pv = Pa[e][cc][nn];
            const float Sv = Sa[e][cc][nn];
            Sa[e][cc][nn] = H;             // H_in for chunk cc
            H = fmaf(Pv, H, Sv);
        }
    }
    __syncthreads();

    // ---- phase C: seeded dual re-scan + fp16 output -----------------------
    {
        h2 D2h;
        D2h[0] = (_Float16)Dp[0];
        D2h[1] = (_Float16)Dp[1];
        const int base = ch * CHUNK;
        float h0 = Sa[0][ch][n], h1 = Sa[1][ch][n];
        for (int i0 = 0; i0 < CHUNK; i0 += 8) {
            float qs[8];
            #pragma unroll
            for (int j = 0; j < 8; ++j) {
                const float4 v = pk[((i0 + j) << 5) + ch];
                const h2 xs2 = __builtin_bit_cast(h2, v.z);
                const h2 gg2 = __builtin_bit_cast(h2, v.w);
                const float Bn = __builtin_amdgcn_fdot2(xs2, wxB2, 0.f, false);
                const float Cn = __builtin_amdgcn_fdot2(xs2, wxC2, 0.f, false);
                const float xs0 = hext(v.z, 0), xs1 = hext(v.z, 16);
                const float g0 = hext(v.w, 0),  g1 = hext(v.w, 16);
                const float dA0 = __builtin_amdgcn_exp2f(v.x * A0);
                const float dA1 = __builtin_amdgcn_exp2f(v.y * A1);
                h0 = fmaf(h0, dA0, (v.x * xs0) * Bn);
                h1 = fmaf(h1, dA1, (v.y * xs1) * Bn);
                float t = h0 * g0;
                t = fmaf(h1, g1, t);
                float q = t * Cn;
                q = dppadd<0xB1>(q);    // xor1
                q = dppadd<0x4E>(q);    // xor2
                q = dppadd<0x141>(q);   // xor4 (row_half_mirror)
                q = dppadd<0x140>(q);   // xor8 (row_mirror) -> 16-lane sum
                const h2 dgh = D2h * gg2;                       // v_pk_mul_f16
                const float dterm = __builtin_amdgcn_fdot2(xs2, dgh, 0.f, false);
                qs[j] = q + dterm;
            }
            if (n == 0) {
                float4 st;
                st.x = __builtin_bit_cast(float, __builtin_amdgcn_cvt_pkrtz(qs[0], qs[1]));
                st.y = __builtin_bit_cast(float, __builtin_amdgcn_cvt_pkrtz(qs[2], qs[3]));
                st.z = __builtin_bit_cast(float, __builtin_amdgcn_cvt_pkrtz(qs[4], qs[5]));
                st.w = __builtin_bit_cast(float, __builtin_amdgcn_cvt_pkrtz(qs[6], qs[7]));
                *reinterpret_cast<float4*>(&a2row[base + i0]) = st;
            }
        }
    }
}

// ---------------------------------------------------------------------------
extern "C" void kernel_launch(void* const* d_in, const int* in_sizes, int n_in,
                              void* d_out, int out_size, void* d_ws, size_t ws_size,
                              hipStream_t stream)
{
    const float* x     = (const float*)d_in[0];
    const float* W1    = (const float*)d_in[1];
    const float* g1    = (const float*)d_in[2];
    const float* b1    = (const float*)d_in[3];
    const float* Win   = (const float*)d_in[4];
    const float* convw = (const float*)d_in[5];
    const float* convb = (const float*)d_in[6];
    const float* Wx    = (const float*)d_in[7];
    const float* Wdt   = (const float*)d_in[8];
    const float* bdt   = (const float*)d_in[9];
    const float* Alog  = (const float*)d_in[10];
    const float* Dp    = (const float*)d_in[11];
    const float* Wout  = (const float*)d_in[12];
    const float* W2    = (const float*)d_in[13];
    const float* g2    = (const float*)d_in[14];
    const float* b2    = (const float*)d_in[15];
    const float* W3    = (const float*)d_in[16];

    unsigned char* base = (unsigned char*)d_ws;   // all regions disjoint
    float* C1 = (float*)(base + 0);               //  8,388,608
    float* P0 = (float*)(base + 8388608);         //  2,097,152
    float* P1 = (float*)(base + 10485760);        //  2,097,152
    float* s1 = (float*)(base + 12582912);        //  8 KB
    float* t1 = (float*)(base + 12591104);        //  8 KB
    float* s2 = (float*)(base + 12599296);        //  2 KB
    float* t2 = (float*)(base + 12601344);        //  2 KB
    float* bnp = (float*)(base + 12615680);       //  524,288 (32 grp x 2 x 2048)
    _Float16* a2  = (_Float16*)(base + 13172736); //  4,194,304
    _Float16* xh  = (_Float16*)(base + 17367040); //  3,670,016
    _Float16* w1h = (_Float16*)(base + 21037056); //  7,340,032
    _Float16* w2h = (_Float16*)(base + 28377088); //  2,097,152
    _Float16* w3h = (_Float16*)(base + 30474240); //    262,144
    _Float16* h3h = (_Float16*)(base + 30736384); //  1,048,576  (end ~31.8 MB)

    // 1) all fp32->fp16 conversions in one grid-filling dispatch
    cvt_all<<<3840, 256, 0, stream>>>(x, W1, W2, W3, xh, w1h, w2h, w3h);

    // 2) GEMM1: C1 = x @ W1^T ; fused BN1 partials into epilogue (dbuf)
    gemm_f16<<<dim3(32, 16, 1), 256, 0, stream>>>(
        xh, w1h, C1, 2048, 1792, 28, 0, bnp, 2048);

    // 3) BN1 finalize (32 partial groups)
    bn_fin<<<8, 256, 0, stream>>>(bnp, 32, 2048, 1.0f / 1024.f, g1, b1, s1, t1);

    // 4) mamba scan: reads C1, writes a2 (fp16)
    mamba_scan9<<<1024, 512, 0, stream>>>(C1, a2, s1, t1, Win, convw, convb,
                                          Wx, Wdt, bdt, Alog, Dp, Wout);

    // 5) GEMM2 (split-K=2, dbuf): P0/P1 = a2 @ W2^T  (1024x512, K=2048)
    gemm_f16<<<dim3(8, 16, 2), 256, 0, stream>>>(
        a2, w2h, P0, 512, 2048, 16, (size_t)1024 * 512, nullptr, 0);

    // 6) BN2 stats over P0+P1 (partials summed before squaring)
    bn_part<<<dim3(8, 16), 256, 0, stream>>>(P0, P1, 64, 512, bnp);
    bn_fin<<<2, 256, 0, stream>>>(bnp, 16, 512, 1.0f / 1024.f, g2, b2, s2, t2);

    // 7) h3 = relu(bn2(P0+P1)) -> fp16
    cvt_bnrelu<<<512, 256, 0, stream>>>(P0, P1, s2, t2, h3h);

    // 8) GEMM3: d_out = h3 @ W3^T  (1024x256, K=512, dbuf)
    gemm_f16<<<dim3(4, 16, 1), 256, 0, stream>>>(
        h3h, w3h, (float*)d_out, 256, 512, 8, 0, nullptr, 0);
}

// Round 13
// 123.863 us; speedup vs baseline: 1.0676x; 1.0233x over previous
//
#include <hip/hip_runtime.h>
#include <math.h>

#define SEQL 2048
#define BATCH 1024
#define CHUNK 64
#define NCH 32

typedef _Float16 f16x8 __attribute__((ext_vector_type(8)));
typedef _Float16 f16x4 __attribute__((ext_vector_type(4)));
typedef _Float16 h2 __attribute__((ext_vector_type(2)));
typedef float f32x4 __attribute__((ext_vector_type(4)));

// ---------------------------------------------------------------------------
// fp16 pack/unpack helpers
// ---------------------------------------------------------------------------
__device__ inline unsigned short f2h(float f) {
    _Float16 h = (_Float16)f;
    return *reinterpret_cast<unsigned short*>(&h);
}
__device__ inline float packh2(float a, float b) {
    return __uint_as_float((unsigned)f2h(a) | ((unsigned)f2h(b) << 16));
}
__device__ inline float hext(float packed, int sh) {
    const unsigned short s = (unsigned short)(__float_as_uint(packed) >> sh);
    _Float16 h = *reinterpret_cast<const _Float16*>(&s);
    return (float)h;
}

__device__ inline void gl2lds16(const void* g, void* l) {
    __builtin_amdgcn_global_load_lds(
        (const __attribute__((address_space(1))) unsigned int*)g,
        (__attribute__((address_space(3))) unsigned int*)l, 16, 0, 0);
}

// DPP cross-lane add: v += dpp_perm(v).
template<int CTRL>
__device__ inline float dppadd(float v) {
    const int p = __builtin_amdgcn_update_dpp(0, __float_as_int(v), CTRL, 0xF, 0xF, true);
    return v + __int_as_float(p);
}

// ---------------------------------------------------------------------------
// Merged fp32->fp16 convert: x (1024 rows, 1775->1792), W1 (2048 rows, same),
// W2 (512 rows, K=2048), W3 (256 rows, K=512).
// ---------------------------------------------------------------------------
__global__ __launch_bounds__(256) void cvt_all(
    const float* __restrict__ x, const float* __restrict__ W1,
    const float* __restrict__ W2, const float* __restrict__ W3,
    _Float16* __restrict__ xh, _Float16* __restrict__ w1h,
    _Float16* __restrict__ w2h, _Float16* __restrict__ w3h)
{
    const int bid = blockIdx.x;
    if (bid < 3072) {
        const float* src; _Float16* dst;
        if (bid < 1024) { src = x + (size_t)bid * 1775;           dst = xh  + (size_t)bid * 1792; }
        else            { src = W1 + (size_t)(bid - 1024) * 1775; dst = w1h + (size_t)(bid - 1024) * 1792; }
        f16x4* dst4 = reinterpret_cast<f16x4*>(dst);
        for (int i = threadIdx.x; i < 448; i += 256) {
            const int k = i * 4;
            float4 v = {0.f, 0.f, 0.f, 0.f};
            if (k + 3 < 1775) v = *reinterpret_cast<const float4*>(&src[k]);
            else {
                if (k     < 1775) v.x = src[k];
                if (k + 1 < 1775) v.y = src[k + 1];
                if (k + 2 < 1775) v.z = src[k + 2];
            }
            f16x4 o; o[0] = (_Float16)v.x; o[1] = (_Float16)v.y; o[2] = (_Float16)v.z; o[3] = (_Float16)v.w;
            dst4[i] = o;
        }
    } else {
        const float* src; _Float16* dst; int nvec;
        if (bid < 3584) { const int r = bid - 3072; src = W2 + (size_t)r * 2048; dst = w2h + (size_t)r * 2048; nvec = 512; }
        else            { const int r = bid - 3584; src = W3 + (size_t)r * 512;  dst = w3h + (size_t)r * 512;  nvec = 128; }
        f16x4* dst4 = reinterpret_cast<f16x4*>(dst);
        for (int i = threadIdx.x; i < nvec; i += 256) {
            const float4 v = reinterpret_cast<const float4*>(src)[i];
            f16x4 o; o[0] = (_Float16)v.x; o[1] = (_Float16)v.y; o[2] = (_Float16)v.z; o[3] = (_Float16)v.w;
            dst4[i] = o;
        }
    }
}

// ---------------------------------------------------------------------------
// fp16 MFMA GEMM (NT), double-buffered LDS: STAGE(t+1) issued before
// ds_read+MFMA of tile t, one barrier per tile. 64x64 tile, BK=64, 4 waves,
// 16x16x32_f16 MFMA, gl2lds staging, XOR slot swizzle on both sides.
// Split-K over blockIdx.z (C += z*coff). If bnp != nullptr (non-split only):
// epilogue writes per-(m-block, wave-half) column sum/sumsq partials.
// ---------------------------------------------------------------------------
__global__ __launch_bounds__(256) void gemm_f16(
    const _Float16* __restrict__ A, const _Float16* __restrict__ B,
    float* __restrict__ C, int ldc, int Kp, int ksteps, size_t coff,
    float* __restrict__ bnp, int bn_ld)
{
    __shared__ __attribute__((aligned(16))) _Float16 sA[2][64 * 64];  // 16 KB
    __shared__ __attribute__((aligned(16))) _Float16 sB[2][64 * 64];  // 16 KB

    const int tid = threadIdx.x;
    const int wave = tid >> 6;
    const int lane = tid & 63;
    const int m0 = blockIdx.y * 64;
    const int n0 = blockIdx.x * 64;
    C += (size_t)blockIdx.z * coff;

    const int srow = tid >> 3;          // 0..31
    const int pslot = tid & 7;
    const int gslot = pslot ^ (srow & 7);
    const size_t gk0 = (size_t)blockIdx.z * ksteps * 64 + (size_t)gslot * 8;
    const _Float16* gA0 = A + (size_t)(m0 + srow) * Kp + gk0;
    const _Float16* gA1 = A + (size_t)(m0 + 32 + srow) * Kp + gk0;
    const _Float16* gB0 = B + (size_t)(n0 + srow) * Kp + gk0;
    const _Float16* gB1 = B + (size_t)(n0 + 32 + srow) * Kp + gk0;
    const int wdst = wave * 512;

    const int wr = wave >> 1, wc = wave & 1;
    const int li = lane & 15, gq = lane >> 4;
    const int p0s = (gq    ) ^ (li & 7);
    const int p1s = (gq + 4) ^ (li & 7);

    f32x4 acc[2][2];
    #pragma unroll
    for (int i = 0; i < 2; ++i)
        #pragma unroll
        for (int j = 0; j < 2; ++j)
            #pragma unroll
            for (int v = 0; v < 4; ++v) acc[i][j][v] = 0.f;

    // prologue: stage tile 0 into buffer 0
    gl2lds16(gA0, &sA[0][wdst]);
    gl2lds16(gA1, &sA[0][2048 + wdst]);
    gl2lds16(gB0, &sB[0][wdst]);
    gl2lds16(gB1, &sB[0][2048 + wdst]);
    __syncthreads();

    int cur = 0;
    for (int kt = 0; kt < ksteps; ++kt) {
        if (kt + 1 < ksteps) {
            const size_t go = (size_t)(kt + 1) * 64;
            const int nb = cur ^ 1;
            gl2lds16(gA0 + go, &sA[nb][wdst]);
            gl2lds16(gA1 + go, &sA[nb][2048 + wdst]);
            gl2lds16(gB0 + go, &sB[nb][wdst]);
            gl2lds16(gB1 + go, &sB[nb][2048 + wdst]);
        }

        f16x8 af[2][2], bg[2][2];
        #pragma unroll
        for (int mi = 0; mi < 2; ++mi) {
            const int rb = (wr * 32 + mi * 16 + li) * 64;
            af[mi][0] = *(const f16x8*)&sA[cur][rb + p0s * 8];
            af[mi][1] = *(const f16x8*)&sA[cur][rb + p1s * 8];
        }
        #pragma unroll
        for (int ni = 0; ni < 2; ++ni) {
            const int rb = (wc * 32 + ni * 16 + li) * 64;
            bg[ni][0] = *(const f16x8*)&sB[cur][rb + p0s * 8];
            bg[ni][1] = *(const f16x8*)&sB[cur][rb + p1s * 8];
        }
        #pragma unroll
        for (int mi = 0; mi < 2; ++mi)
            #pragma unroll
            for (int ni = 0; ni < 2; ++ni) {
                acc[mi][ni] = __builtin_amdgcn_mfma_f32_16x16x32_f16(af[mi][0], bg[ni][0], acc[mi][ni], 0, 0, 0);
                acc[mi][ni] = __builtin_amdgcn_mfma_f32_16x16x32_f16(af[mi][1], bg[ni][1], acc[mi][ni], 0, 0, 0);
            }
        __syncthreads();
        cur ^= 1;
    }

    #pragma unroll
    for (int mi = 0; mi < 2; ++mi)
        #pragma unroll
        for (int ni = 0; ni < 2; ++ni) {
            const int col = n0 + wc * 32 + ni * 16 + li;
            #pragma unroll
            for (int i = 0; i < 4; ++i) {
                const int row = m0 + wr * 32 + mi * 16 + gq * 4 + i;
                C[(size_t)row * ldc + col] = acc[mi][ni][i];
            }
        }

    // ---- optional fused batchnorm partials -------------------------------
    if (bnp) {
        #pragma unroll
        for (int ni = 0; ni < 2; ++ni) {
            float ps = 0.f, pq = 0.f;
            #pragma unroll
            for (int mi = 0; mi < 2; ++mi)
                #pragma unroll
                for (int i = 0; i < 4; ++i) {
                    const float v = acc[mi][ni][i];
                    ps += v; pq += v * v;
                }
            ps += __shfl_xor(ps, 16); ps += __shfl_xor(ps, 32);
            pq += __shfl_xor(pq, 16); pq += __shfl_xor(pq, 32);
            if (gq == 0) {
                const int col = n0 + wc * 32 + ni * 16 + li;
                const int grp = blockIdx.y * 2 + wr;
                bnp[(size_t)(grp * 2    ) * bn_ld + col] = ps;
                bnp[(size_t)(grp * 2 + 1) * bn_ld + col] = pq;
            }
        }
    }
}

// ---------------------------------------------------------------------------
// GEMM3 with the whole BN2 tail fused:
//  - prologue: finalize s2/t2 from bnp partials into LDS (same formula/order
//    as bn_fin -> bit-identical)
//  - A-staging: reg-staged from P0+P1 with fused bn+relu+fp16 cvt.
//    Global read at linear slot pslot (coalesced); ds_write to physical slot
//    pslot^(row&7) -> matches read-side gq^(li&7), conflict-free banks.
//  - B-staging: gl2lds of w3h (pre-swizzled global source), double-buffered.
// Replaces bn_fin(BN2) + cvt_bnrelu + gemm_f16(GEMM3) = 3 dispatches -> 1.
// ---------------------------------------------------------------------------
__global__ __launch_bounds__(256) void gemm3_fused(
    const float* __restrict__ P0, const float* __restrict__ P1,
    const float* __restrict__ bnp,
    const float* __restrict__ g2, const float* __restrict__ b2,
    const _Float16* __restrict__ B, float* __restrict__ C)
{
    __shared__ __attribute__((aligned(16))) _Float16 sA[2][64 * 64];  // 16 KB
    __shared__ __attribute__((aligned(16))) _Float16 sB[2][64 * 64];  // 16 KB
    __shared__ __attribute__((aligned(16))) float s2l[512];           //  2 KB
    __shared__ __attribute__((aligned(16))) float t2l[512];           //  2 KB

    const int tid = threadIdx.x;
    const int wave = tid >> 6;
    const int lane = tid & 63;
    const int m0 = blockIdx.y * 64;
    const int n0 = blockIdx.x * 64;

    const int srow = tid >> 3;          // 0..31
    const int pslot = tid & 7;
    const int gslot = pslot ^ (srow & 7);      // B-side global slot
    const int wslot = gslot * 8;               // A-side physical write slot
    const _Float16* gB0 = B + (size_t)(n0 + srow) * 512 + gslot * 8;
    const _Float16* gB1 = B + (size_t)(n0 + 32 + srow) * 512 + gslot * 8;
    const int wdst = wave * 512;

    const float* gP00 = P0 + (size_t)(m0 + srow) * 512 + pslot * 8;
    const float* gP01 = P0 + (size_t)(m0 + 32 + srow) * 512 + pslot * 8;
    const float* gP10 = P1 + (size_t)(m0 + srow) * 512 + pslot * 8;
    const float* gP11 = P1 + (size_t)(m0 + 32 + srow) * 512 + pslot * 8;

    // ---- prologue: BN2 finalize into LDS ---------------------------------
    for (int c = tid; c < 512; c += 256) {
        float sum = 0.f, sq = 0.f;
        #pragma unroll
        for (int z = 0; z < 16; ++z) {
            sum += bnp[(size_t)(z * 2    ) * 512 + c];
            sq  += bnp[(size_t)(z * 2 + 1) * 512 + c];
        }
        const float mean = sum * (1.0f / 1024.f);
        const float var = fmaxf(sq * (1.0f / 1024.f) - mean * mean, 0.f);
        const float rstd = 1.0f / sqrtf(var + 1e-5f);
        const float sv = g2[c] * rstd;
        s2l[c] = sv;
        t2l[c] = b2[c] - mean * sv;
    }

    // stage A tile kt into buffer b: load fp32 P0+P1, bn+relu+cvt, ds_write
    auto stageA = [&](int kt, int b) {
        const int kc = kt * 64 + pslot * 8;
        const float4 a0 = *reinterpret_cast<const float4*>(gP00 + kt * 64);
        const float4 a1 = *reinterpret_cast<const float4*>(gP00 + kt * 64 + 4);
        const float4 c0 = *reinterpret_cast<const float4*>(gP10 + kt * 64);
        const float4 c1 = *reinterpret_cast<const float4*>(gP10 + kt * 64 + 4);
        const float4 d0 = *reinterpret_cast<const float4*>(gP01 + kt * 64);
        const float4 d1 = *reinterpret_cast<const float4*>(gP01 + kt * 64 + 4);
        const float4 e0 = *reinterpret_cast<const float4*>(gP11 + kt * 64);
        const float4 e1 = *reinterpret_cast<const float4*>(gP11 + kt * 64 + 4);
        const float4 sv0 = *reinterpret_cast<const float4*>(&s2l[kc]);
        const float4 sv1 = *reinterpret_cast<const float4*>(&s2l[kc + 4]);
        const float4 tv0 = *reinterpret_cast<const float4*>(&t2l[kc]);
        const float4 tv1 = *reinterpret_cast<const float4*>(&t2l[kc + 4]);
        f16x8 o;
        o[0] = (_Float16)fmaxf(fmaf(sv0.x, a0.x + c0.x, tv0.x), 0.f);
        o[1] = (_Float16)fmaxf(fmaf(sv0.y, a0.y + c0.y, tv0.y), 0.f);
        o[2] = (_Float16)fmaxf(fmaf(sv0.z, a0.z + c0.z, tv0.z), 0.f);
        o[3] = (_Float16)fmaxf(fmaf(sv0.w, a0.w + c0.w, tv0.w), 0.f);
        o[4] = (_Float16)fmaxf(fmaf(sv1.x, a1.x + c1.x, tv1.x), 0.f);
        o[5] = (_Float16)fmaxf(fmaf(sv1.y, a1.y + c1.y, tv1.y), 0.f);
        o[6] = (_Float16)fmaxf(fmaf(sv1.z, a1.z + c1.z, tv1.z), 0.f);
        o[7] = (_Float16)fmaxf(fmaf(sv1.w, a1.w + c1.w, tv1.w), 0.f);
        *reinterpret_cast<f16x8*>(&sA[b][srow * 64 + wslot]) = o;
        f16x8 p;
        p[0] = (_Float16)fmaxf(fmaf(sv0.x, d0.x + e0.x, tv0.x), 0.f);
        p[1] = (_Float16)fmaxf(fmaf(sv0.y, d0.y + e0.y, tv0.y), 0.f);
        p[2] = (_Float16)fmaxf(fmaf(sv0.z, d0.z + e0.z, tv0.z), 0.f);
        p[3] = (_Float16)fmaxf(fmaf(sv0.w, d0.w + e0.w, tv0.w), 0.f);
        p[4] = (_Float16)fmaxf(fmaf(sv1.x, d1.x + e1.x, tv1.x), 0.f);
        p[5] = (_Float16)fmaxf(fmaf(sv1.y, d1.y + e1.y, tv1.y), 0.f);
        p[6] = (_Float16)fmaxf(fmaf(sv1.z, d1.z + e1.z, tv1.z), 0.f);
        p[7] = (_Float16)fmaxf(fmaf(sv1.w, d1.w + e1.w, tv1.w), 0.f);
        *reinterpret_cast<f16x8*>(&sA[b][(srow + 32) * 64 + wslot]) = p;
    };

    const int wr = wave >> 1, wc = wave & 1;
    const int li = lane & 15, gq = lane >> 4;
    const int p0s = (gq    ) ^ (li & 7);
    const int p1s = (gq + 4) ^ (li & 7);

    f32x4 acc[2][2];
    #pragma unroll
    for (int i = 0; i < 2; ++i)
        #pragma unroll
        for (int j = 0; j < 2; ++j)
            #pragma unroll
            for (int v = 0; v < 4; ++v) acc[i][j][v] = 0.f;

    // prologue staging: B0 (gl2lds) in flight across the s2l barrier; A0 after
    gl2lds16(gB0, &sB[0][wdst]);
    gl2lds16(gB1, &sB[0][2048 + wdst]);
    __syncthreads();                 // s2l/t2l visible (B0 also drained)
    stageA(0, 0);
    __syncthreads();                 // A0 visible

    int cur = 0;
    for (int kt = 0; kt < 8; ++kt) {
        if (kt + 1 < 8) {
            const int nb = cur ^ 1;
            gl2lds16(gB0 + (size_t)(kt + 1) * 64, &sB[nb][wdst]);
            gl2lds16(gB1 + (size_t)(kt + 1) * 64, &sB[nb][2048 + wdst]);
            stageA(kt + 1, nb);      // writes nb: nobody reads nb this phase
        }

        f16x8 af[2][2], bg[2][2];
        #pragma unroll
        for (int mi = 0; mi < 2; ++mi) {
            const int rb = (wr * 32 + mi * 16 + li) * 64;
            af[mi][0] = *(const f16x8*)&sA[cur][rb + p0s * 8];
            af[mi][1] = *(const f16x8*)&sA[cur][rb + p1s * 8];
        }
        #pragma unroll
        for (int ni = 0; ni < 2; ++ni) {
            const int rb = (wc * 32 + ni * 16 + li) * 64;
            bg[ni][0] = *(const f16x8*)&sB[cur][rb + p0s * 8];
            bg[ni][1] = *(const f16x8*)&sB[cur][rb + p1s * 8];
        }
        #pragma unroll
        for (int mi = 0; mi < 2; ++mi)
            #pragma unroll
            for (int ni = 0; ni < 2; ++ni) {
                acc[mi][ni] = __builtin_amdgcn_mfma_f32_16x16x32_f16(af[mi][0], bg[ni][0], acc[mi][ni], 0, 0, 0);
                acc[mi][ni] = __builtin_amdgcn_mfma_f32_16x16x32_f16(af[mi][1], bg[ni][1], acc[mi][ni], 0, 0, 0);
            }
        __syncthreads();
        cur ^= 1;
    }

    #pragma unroll
    for (int mi = 0; mi < 2; ++mi)
        #pragma unroll
        for (int ni = 0; ni < 2; ++ni) {
            const int col = n0 + wc * 32 + ni * 16 + li;
            #pragma unroll
            for (int i = 0; i < 4; ++i) {
                const int row = m0 + wr * 32 + mi * 16 + gq * 4 + i;
                C[(size_t)row * 256 + col] = acc[mi][ni][i];
            }
        }
}

// ---------------------------------------------------------------------------
// Batchnorm partials (BN2 over P0+P1) and BN1 finalize.
// ---------------------------------------------------------------------------
__global__ __launch_bounds__(256) void bn_part(
    const float* __restrict__ X, const float* __restrict__ X2,
    int rows_per, int ld, float* __restrict__ part)
{
    __shared__ float rs[4][64], rq[4][64];
    const int tid = threadIdx.x;
    const int c = tid & 63, rg4 = tid >> 6;
    const int col = blockIdx.x * 64 + c;
    const int r0 = blockIdx.y * rows_per;
    float sum = 0.f, sq = 0.f;
    for (int r = rg4; r < rows_per; r += 4) {
        const size_t idx = (size_t)(r0 + r) * ld + col;
        float v = X[idx];
        if (X2) v += X2[idx];
        sum += v; sq += v * v;
    }
    rs[rg4][c] = sum; rq[rg4][c] = sq;
    __syncthreads();
    if (rg4 == 0) {
        sum = rs[0][c] + rs[1][c] + rs[2][c] + rs[3][c];
        sq  = rq[0][c] + rq[1][c] + rq[2][c] + rq[3][c];
        part[((size_t)blockIdx.y * 2    ) * ld + col] = sum;
        part[((size_t)blockIdx.y * 2 + 1) * ld + col] = sq;
    }
}

__global__ __launch_bounds__(256) void bn_fin(
    const float* __restrict__ part, int RG, int ld, float inv_rows,
    const float* __restrict__ g, const float* __restrict__ b,
    float* __restrict__ s, float* __restrict__ t)
{
    const int col = blockIdx.x * 256 + threadIdx.x;
    if (col >= ld) return;
    float sum = 0.f, sq = 0.f;
    for (int z = 0; z < RG; ++z) {
        sum += part[((size_t)z * 2    ) * ld + col];
        sq  += part[((size_t)z * 2 + 1) * ld + col];
    }
    const float mean = sum * inv_rows;
    const float var = fmaxf(sq * inv_rows - mean * mean, 0.f);
    const float rstd = 1.0f / sqrtf(var + 1e-5f);
    const float sv = g[col] * rstd;
    s[col] = sv;
    t[col] = b[col] - mean * sv;
}

// ---------------------------------------------------------------------------
// Chunked-parallel mamba scan, v9 (unchanged): step-major pk, e-paired lanes,
// 32 chunks x 64 steps, DPP reduction, fp16 output.
// ---------------------------------------------------------------------------
__global__ __launch_bounds__(512, 8) void mamba_scan9(
    const float* __restrict__ Y, _Float16* __restrict__ a2,
    const float* __restrict__ s1, const float* __restrict__ t1,
    const float* __restrict__ Win, const float* __restrict__ convw,
    const float* __restrict__ convb, const float* __restrict__ Wx,
    const float* __restrict__ Wdt, const float* __restrict__ bdt,
    const float* __restrict__ Alog, const float* __restrict__ Dp,
    const float* __restrict__ Wout)
{
    __shared__ __align__(16) float4 pk[SEQL];   // 32 KB, index = (i<<5) + ch
    __shared__ float Pa[2][NCH][16];            // 4 KB
    __shared__ float Sa[2][NCH][16];            // 4 KB (becomes Hin in-place)

    const int tid = threadIdx.x;
    const int row = blockIdx.x;
    const float* yrow = Y + (size_t)row * SEQL;
    _Float16* a2row = a2 + (size_t)row * SEQL;

    // ---- phase A': steps [4*tid, 4*tid+4) ---------------------------------
    {
        const int l0 = tid * 4;
        float4 ym = {0.f,0.f,0.f,0.f}, sm = {0.f,0.f,0.f,0.f}, tm = {0.f,0.f,0.f,0.f};
        if (tid > 0) {
            ym = *reinterpret_cast<const float4*>(&yrow[l0 - 4]);
            sm = *reinterpret_cast<const float4*>(&s1[l0 - 4]);
            tm = *reinterpret_cast<const float4*>(&t1[l0 - 4]);
        }
        const float4 y0 = *reinterpret_cast<const float4*>(&yrow[l0]);
        const float4 s0 = *reinterpret_cast<const float4*>(&s1[l0]);
        const float4 t0 = *reinterpret_cast<const float4*>(&t1[l0]);

        float ua[8];
        ua[0] = fmaf(sm.x, ym.x, tm.x);
        ua[1] = fmaf(sm.y, ym.y, tm.y);
        ua[2] = fmaf(sm.z, ym.z, tm.z);
        ua[3] = fmaf(sm.w, ym.w, tm.w);
        ua[4] = fmaf(s0.x, y0.x, t0.x);
        ua[5] = fmaf(s0.y, y0.y, t0.y);
        ua[6] = fmaf(s0.z, y0.z, t0.z);
        ua[7] = fmaf(s0.w, y0.w, t0.w);

        const float wi0 = Win[0], wi1 = Win[1];
        const float wz0 = Win[2], wz1 = Win[3];
        const float wo0 = Wout[0], wo1 = Wout[1];
        const float cw00 = convw[0], cw01 = convw[1], cw02 = convw[2], cw03 = convw[3];
        const float cw10 = convw[4], cw11 = convw[5], cw12 = convw[6], cw13 = convw[7];
        const float cb0 = convb[0], cb1 = convb[1];
        const float wx00 = Wx[0], wx01 = Wx[1];
        const float wdt0 = Wdt[0], wdt1 = Wdt[1];
        const float bdt0 = bdt[0], bdt1 = bdt[1];

        #pragma unroll
        for (int j = 0; j < 4; ++j) {
            const int l = l0 + j;
            const float u0 = ua[j + 4], um1 = ua[j + 3], um2 = ua[j + 2], um3 = ua[j + 1];
            const float c0 = fmaf(wi0, cw00 * um3 + cw01 * um2 + cw02 * um1 + cw03 * u0, cb0);
            const float c1 = fmaf(wi1, cw10 * um3 + cw11 * um2 + cw12 * um1 + cw13 * u0, cb1);
            const float xs0 = c0 / (1.f + __expf(-c0));
            const float xs1 = c1 / (1.f + __expf(-c1));
            const float d0 = xs0 * wx00 + xs1 * wx01;
            const float dt0 = __logf(1.f + __expf(fmaf(d0, wdt0, bdt0)));
            const float dt1 = __logf(1.f + __expf(fmaf(d0, wdt1, bdt1)));
            const float z0 = u0 * wz0, z1 = u0 * wz1;
            const float g0 = (z0 / (1.f + __expf(-z0))) * wo0;
            const float g1 = (z1 / (1.f + __expf(-z1))) * wo1;
            float4 rec;
            rec.x = dt0; rec.y = dt1;
            rec.z = packh2(xs0, xs1);
            rec.w = packh2(g0, g1);
            pk[((l & 63) << 5) + (l >> 6)] = rec;   // step-major
        }
    }
    __syncthreads();

    // ---- lane decomposition: chunk = 16 lanes, lane = n -------------------
    const int ch = tid >> 4;       // chunk 0..31
    const int n  = tid & 15;

    const float A0 = -__expf(Alog[n])      * 1.44269504f;  // e=0, * log2(e)
    const float A1 = -__expf(Alog[16 + n]) * 1.44269504f;  // e=1
    h2 wxB2, wxC2;
    wxB2[0] = (_Float16)Wx[(1 + n) * 2 + 0];
    wxB2[1] = (_Float16)Wx[(1 + n) * 2 + 1];
    wxC2[0] = (_Float16)Wx[(17 + n) * 2 + 0];
    wxC2[1] = (_Float16)Wx[(17 + n) * 2 + 1];

    // ---- phase A'': dual local scan, h_in = 0 -----------------------------
    {
        float h0 = 0.f, h1 = 0.f, p0 = 1.f, p1 = 1.f;
        for (int i0 = 0; i0 < CHUNK; i0 += 8) {
            #pragma unroll
            for (int j = 0; j < 8; ++j) {
                const float4 v = pk[((i0 + j) << 5) + ch];
                const h2 xs2 = __builtin_bit_cast(h2, v.z);
                const float Bn = __builtin_amdgcn_fdot2(xs2, wxB2, 0.f, false);
                const float xs0 = hext(v.z, 0), xs1 = hext(v.z, 16);
                const float dA0 = __builtin_amdgcn_exp2f(v.x * A0);
                const float dA1 = __builtin_amdgcn_exp2f(v.y * A1);
                h0 = fmaf(h0, dA0, (v.x * xs0) * Bn);
                h1 = fmaf(h1, dA1, (v.y * xs1) * Bn);
                p0 *= dA0; p1 *= dA1;
            }
        }
        Pa[0][ch][n] = p0; Pa[1][ch][n] = p1;
        Sa[0][ch][n] = h0; Sa[1][ch][n] = h1;
    }
    __syncthreads();

    // ---- phase B: serial chunk combine (in-place Hin into Sa) -------------
    if (tid < 32) {
        const int e = tid >> 4, nn = tid & 15;
        float H = 0.f;
        #pragma unroll
        for (int cc = 0; cc < NCH; ++cc) {
            const float Pv = Pa[e][cc][nn];
            const float Sv = Sa[e][cc][nn];
            Sa[e][cc][nn] = H;             // H_in for chunk cc
            H = fmaf(Pv, H, Sv);
        }
    }
    __syncthreads();

    // ---- phase C: seeded dual re-scan + fp16 output -----------------------
    {
        h2 D2h;
        D2h[0] = (_Float16)Dp[0];
        D2h[1] = (_Float16)Dp[1];
        const int base = ch * CHUNK;
        float h0 = Sa[0][ch][n], h1 = Sa[1][ch][n];
        for (int i0 = 0; i0 < CHUNK; i0 += 8) {
            float qs[8];
            #pragma unroll
            for (int j = 0; j < 8; ++j) {
                const float4 v = pk[((i0 + j) << 5) + ch];
                const h2 xs2 = __builtin_bit_cast(h2, v.z);
                const h2 gg2 = __builtin_bit_cast(h2, v.w);
                const float Bn = __builtin_amdgcn_fdot2(xs2, wxB2, 0.f, false);
                const float Cn = __builtin_amdgcn_fdot2(xs2, wxC2, 0.f, false);
                const float xs0 = hext(v.z, 0), xs1 = hext(v.z, 16);
                const float g0 = hext(v.w, 0),  g1 = hext(v.w, 16);
                const float dA0 = __builtin_amdgcn_exp2f(v.x * A0);
                const float dA1 = __builtin_amdgcn_exp2f(v.y * A1);
                h0 = fmaf(h0, dA0, (v.x * xs0) * Bn);
                h1 = fmaf(h1, dA1, (v.y * xs1) * Bn);
                float t = h0 * g0;
                t = fmaf(h1, g1, t);
                float q = t * Cn;
                q = dppadd<0xB1>(q);    // xor1
                q = dppadd<0x4E>(q);    // xor2
                q = dppadd<0x141>(q);   // xor4 (row_half_mirror)
                q = dppadd<0x140>(q);   // xor8 (row_mirror) -> 16-lane sum
                const h2 dgh = D2h * gg2;                       // v_pk_mul_f16
                const float dterm = __builtin_amdgcn_fdot2(xs2, dgh, 0.f, false);
                qs[j] = q + dterm;
            }
            if (n == 0) {
                float4 st;
                st.x = __builtin_bit_cast(float, __builtin_amdgcn_cvt_pkrtz(qs[0], qs[1]));
                st.y = __builtin_bit_cast(float, __builtin_amdgcn_cvt_pkrtz(qs[2], qs[3]));
                st.z = __builtin_bit_cast(float, __builtin_amdgcn_cvt_pkrtz(qs[4], qs[5]));
                st.w = __builtin_bit_cast(float, __builtin_amdgcn_cvt_pkrtz(qs[6], qs[7]));
                *reinterpret_cast<float4*>(&a2row[base + i0]) = st;
            }
        }
    }
}

// ---------------------------------------------------------------------------
extern "C" void kernel_launch(void* const* d_in, const int* in_sizes, int n_in,
                              void* d_out, int out_size, void* d_ws, size_t ws_size,
                              hipStream_t stream)
{
    const float* x     = (const float*)d_in[0];
    const float* W1    = (const float*)d_in[1];
    const float* g1    = (const float*)d_in[2];
    const float* b1    = (const float*)d_in[3];
    const float* Win   = (const float*)d_in[4];
    const float* convw = (const float*)d_in[5];
    const float* convb = (const float*)d_in[6];
    const float* Wx    = (const float*)d_in[7];
    const float* Wdt   = (const float*)d_in[8];
    const float* bdt   = (const float*)d_in[9];
    const float* Alog  = (const float*)d_in[10];
    const float* Dp    = (const float*)d_in[11];
    const float* Wout  = (const float*)d_in[12];
    const float* W2    = (const float*)d_in[13];
    const float* g2    = (const float*)d_in[14];
    const float* b2    = (const float*)d_in[15];
    const float* W3    = (const float*)d_in[16];

    unsigned char* base = (unsigned char*)d_ws;   // all regions disjoint
    float* C1 = (float*)(base + 0);               //  8,388,608
    float* P0 = (float*)(base + 8388608);         //  2,097,152
    float* P1 = (float*)(base + 10485760);        //  2,097,152
    float* s1 = (float*)(base + 12582912);        //  8 KB
    float* t1 = (float*)(base + 12591104);        //  8 KB
    float* bnp = (float*)(base + 12615680);       //  524,288 (32 grp x 2 x 2048)
    _Float16* a2  = (_Float16*)(base + 13172736); //  4,194,304
    _Float16* xh  = (_Float16*)(base + 17367040); //  3,670,016
    _Float16* w1h = (_Float16*)(base + 21037056); //  7,340,032
    _Float16* w2h = (_Float16*)(base + 28377088); //  2,097,152
    _Float16* w3h = (_Float16*)(base + 30474240); //    262,144

    // 1) all fp32->fp16 conversions in one grid-filling dispatch
    cvt_all<<<3840, 256, 0, stream>>>(x, W1, W2, W3, xh, w1h, w2h, w3h);

    // 2) GEMM1: C1 = x @ W1^T ; fused BN1 partials into epilogue (dbuf)
    gemm_f16<<<dim3(32, 16, 1), 256, 0, stream>>>(
        xh, w1h, C1, 2048, 1792, 28, 0, bnp, 2048);

    // 3) BN1 finalize (32 partial groups)
    bn_fin<<<8, 256, 0, stream>>>(bnp, 32, 2048, 1.0f / 1024.f, g1, b1, s1, t1);

    // 4) mamba scan: reads C1, writes a2 (fp16)
    mamba_scan9<<<1024, 512, 0, stream>>>(C1, a2, s1, t1, Win, convw, convb,
                                          Wx, Wdt, bdt, Alog, Dp, Wout);

    // 5) GEMM2 (split-K=2, dbuf): P0/P1 = a2 @ W2^T  (1024x512, K=2048)
    gemm_f16<<<dim3(8, 16, 2), 256, 0, stream>>>(
        a2, w2h, P0, 512, 2048, 16, (size_t)1024 * 512, nullptr, 0);

    // 6) BN2 partials over P0+P1 (summed before squaring)
    bn_part<<<dim3(8, 16), 256, 0, stream>>>(P0, P1, 64, 512, bnp);

    // 7) GEMM3 with fused BN2-finalize + bn+relu+cvt A-staging -> d_out
    gemm3_fused<<<dim3(4, 16), 256, 0, stream>>>(
        P0, P1, bnp, g2, b2, w3h, (float*)d_out);
}